// Round 4
// baseline (454.912 us; speedup 1.0000x reference)
//
#include <hip/hip_runtime.h>
#include <hip/hip_bf16.h>
#include <math.h>

#define EE 768
#define HH 4
#define KK 36
#define BSN 2048

typedef __attribute__((ext_vector_type(8))) short short8;
typedef __attribute__((ext_vector_type(4))) short short4v;
typedef __attribute__((ext_vector_type(4))) float float4v;

__device__ inline short f2bf(float x){
  return __builtin_bit_cast(short, __float2bfloat16(x));
}
__device__ inline float bf2f(short s){
  return __bfloat162float(__builtin_bit_cast(__hip_bfloat16, s));
}
__device__ inline float gelu_tanh(float x){
  // jax.nn.gelu default (approximate=True)
  float t = tanhf(0.79788456080286536f * (x + 0.044715f * x * x * x));
  return 0.5f * x * (1.0f + t);
}
__device__ __forceinline__ void gload_lds16(const short* g, short* l){
  __builtin_amdgcn_global_load_lds(
      (const __attribute__((address_space(1))) void*)g,
      (__attribute__((address_space(3))) void*)l,
      16, 0, 0);
}

// ---------------------------------------------------------------------------
// v[h][e] = g[h][e] * sum_f W1[h][e][f] * W2y[h][f]    (one wave per (h,e))
// also initializes b1p = b1 (first 12 blocks' worth of threads)
// ---------------------------------------------------------------------------
__global__ __launch_bounds__(256) void k_v(const float* __restrict__ W1,
                                           const float* __restrict__ W2y,
                                           const float* __restrict__ g,
                                           const float* __restrict__ b1,
                                           float* __restrict__ v,
                                           float* __restrict__ b1p){
  const int wid  = blockIdx.x * 4 + (threadIdx.x >> 6);
  const int lane = threadIdx.x & 63;
  const int h = wid / EE, e = wid % EE;
  const float* W  = W1 + ((size_t)h * EE + e) * EE;
  const float* wy = W2y + h * EE;
  float acc = 0.f;
  #pragma unroll
  for (int j = 0; j < 12; ++j){
    int f = lane + 64 * j;
    acc += W[f] * wy[f];
  }
  #pragma unroll
  for (int off = 32; off; off >>= 1) acc += __shfl_xor(acc, off);
  if (lane == 0) v[h * EE + e] = g[h * EE + e] * acc;

  int idx = blockIdx.x * 256 + threadIdx.x;
  if (idx < HH * EE) b1p[idx] = b1[idx];
}

// ---------------------------------------------------------------------------
// b1p[h][f] += sum_e beta[h][e] * W1[h][e][f]   (partial e-chunks + atomics)
// grid: 256 blocks = 4 h * 64 e-chunks of 12
// ---------------------------------------------------------------------------
__global__ __launch_bounds__(256) void k_b1p_acc(const float* __restrict__ W1,
                                                 const float* __restrict__ beta,
                                                 float* __restrict__ b1p){
  const int h   = blockIdx.x >> 6;
  const int ec0 = (blockIdx.x & 63) * 12;
  const float* W  = W1 + (size_t)h * EE * EE;
  const float* bt = beta + h * EE;
  const int f = threadIdx.x;
  float a0 = 0.f, a1 = 0.f, a2 = 0.f;
  #pragma unroll
  for (int e = ec0; e < ec0 + 12; ++e){
    float be = bt[e];
    const float* row = W + (size_t)e * EE;
    a0 += be * row[f];
    a1 += be * row[f + 256];
    a2 += be * row[f + 512];
  }
  atomicAdd(&b1p[h * EE + f],       a0);
  atomicAdd(&b1p[h * EE + f + 256], a1);
  atomicAdd(&b1p[h * EE + f + 512], a2);
}

// ---------------------------------------------------------------------------
// W1t[h][f][e] = bf16( g[h][e] * W1[h][e][f] )   (transposed, bf16)
// grid (24 e-tiles, 24 f-tiles, 4 h), 256 threads
// ---------------------------------------------------------------------------
__global__ __launch_bounds__(256) void k_tW1(const float* __restrict__ W1,
                                             const float* __restrict__ g,
                                             short* __restrict__ W1t){
  __shared__ float tile[32][33];
  const int h  = blockIdx.z;
  const int e0 = blockIdx.x * 32, f0 = blockIdx.y * 32;
  const int tx = threadIdx.x & 31, ty = threadIdx.x >> 5;
  const float* W = W1 + (size_t)h * EE * EE;
  #pragma unroll
  for (int i = 0; i < 4; ++i){
    int e = e0 + ty + 8 * i;
    tile[ty + 8 * i][tx] = W[(size_t)e * EE + f0 + tx] * g[h * EE + e];
  }
  __syncthreads();
  #pragma unroll
  for (int i = 0; i < 4; ++i){
    int f = f0 + ty + 8 * i;
    W1t[((size_t)h * EE + f) * EE + e0 + tx] = f2bf(tile[tx][ty + 8 * i]);
  }
}

// ---------------------------------------------------------------------------
// Wmt[f][c] = bf16( Wm[c][f] )   c in [0,3072), f in [0,768)
// grid (96 c-tiles, 24 f-tiles)
// ---------------------------------------------------------------------------
__global__ __launch_bounds__(256) void k_tWm(const float* __restrict__ Wm,
                                             short* __restrict__ Wmt){
  __shared__ float tile[32][33];
  const int c0 = blockIdx.x * 32, f0 = blockIdx.y * 32;
  const int tx = threadIdx.x & 31, ty = threadIdx.x >> 5;
  #pragma unroll
  for (int i = 0; i < 4; ++i){
    tile[ty + 8 * i][tx] = Wm[(size_t)(c0 + ty + 8 * i) * EE + f0 + tx];
  }
  __syncthreads();
  #pragma unroll
  for (int i = 0; i < 4; ++i){
    Wmt[(size_t)(f0 + ty + 8 * i) * (HH * EE) + c0 + tx] = f2bf(tile[tx][ty + 8 * i]);
  }
}

// ---------------------------------------------------------------------------
// Flash-style fused y pass: ONE WAVE PER ROW n. For each k-row: LN0 ->
// logits d_h = yn . v_h (x_/W2x/b2 cancel in softmax) -> online softmax
// -> acc_h += w * yn. No LDS, no barriers; 2-row register prefetch.
// ---------------------------------------------------------------------------
__global__ __launch_bounds__(256) void k_pass_y(const float* __restrict__ y,
                                                const float* __restrict__ v,
                                                short* __restrict__ p_y){
  const int wave = threadIdx.x >> 6, lane = threadIdx.x & 63;
  const int n = blockIdx.x * 4 + wave;
  const float* base = y + (size_t)n * KK * EE + 4 * lane;

  float4v vreg[HH][3];
  #pragma unroll
  for (int h = 0; h < HH; ++h)
    #pragma unroll
    for (int j = 0; j < 3; ++j)
      vreg[h][j] = *(const float4v*)(v + h * EE + 4 * lane + 256 * j);

  float4v acc[HH][3];
  #pragma unroll
  for (int h = 0; h < HH; ++h)
    #pragma unroll
    for (int j = 0; j < 3; ++j)
      acc[h][j] = (float4v){0.f, 0.f, 0.f, 0.f};
  float m[HH], l[HH];
  #pragma unroll
  for (int h = 0; h < HH; ++h){ m[h] = -INFINITY; l[h] = 0.f; }

  float4v bufA[3], bufB[3];
  #pragma unroll
  for (int j = 0; j < 3; ++j) bufA[j] = *(const float4v*)(base + 256 * j);
  #pragma unroll
  for (int j = 0; j < 3; ++j) bufB[j] = *(const float4v*)(base + EE + 256 * j);

  #pragma unroll 2
  for (int k = 0; k < KK; ++k){
    float4v cur[3];
    #pragma unroll
    for (int j = 0; j < 3; ++j) cur[j] = bufA[j];
    #pragma unroll
    for (int j = 0; j < 3; ++j) bufA[j] = bufB[j];
    if (k + 2 < KK){
      const float* rp = base + (size_t)(k + 2) * EE;
      #pragma unroll
      for (int j = 0; j < 3; ++j) bufB[j] = *(const float4v*)(rp + 256 * j);
    }

    float s = 0.f, s2 = 0.f;
    #pragma unroll
    for (int j = 0; j < 3; ++j)
      #pragma unroll
      for (int c = 0; c < 4; ++c){ float t = cur[j][c]; s += t; s2 += t * t; }
    #pragma unroll
    for (int off = 32; off; off >>= 1){
      s  += __shfl_xor(s, off);
      s2 += __shfl_xor(s2, off);
    }
    const float mu = s * (1.f / EE);
    const float rs = rsqrtf(s2 * (1.f / EE) - mu * mu + 1e-5f);

    float d[HH] = {0.f, 0.f, 0.f, 0.f};
    #pragma unroll
    for (int j = 0; j < 3; ++j)
      #pragma unroll
      for (int c = 0; c < 4; ++c){
        float t = (cur[j][c] - mu) * rs;
        cur[j][c] = t;
        d[0] += t * vreg[0][j][c];
        d[1] += t * vreg[1][j][c];
        d[2] += t * vreg[2][j][c];
        d[3] += t * vreg[3][j][c];
      }
    #pragma unroll
    for (int off = 32; off; off >>= 1){
      d[0] += __shfl_xor(d[0], off);
      d[1] += __shfl_xor(d[1], off);
      d[2] += __shfl_xor(d[2], off);
      d[3] += __shfl_xor(d[3], off);
    }

    #pragma unroll
    for (int h = 0; h < HH; ++h){
      if (d[h] > m[h]){
        float sc = __expf(m[h] - d[h]);   // first iter: exp(-inf)=0
        l[h] *= sc;
        #pragma unroll
        for (int j = 0; j < 3; ++j)
          #pragma unroll
          for (int c = 0; c < 4; ++c) acc[h][j][c] *= sc;
        m[h] = d[h];
      }
      float w = __expf(d[h] - m[h]);
      l[h] += w;
      #pragma unroll
      for (int j = 0; j < 3; ++j)
        #pragma unroll
        for (int c = 0; c < 4; ++c) acc[h][j][c] += w * cur[j][c];
    }
  }

  #pragma unroll
  for (int h = 0; h < HH; ++h){
    const float inv = 1.f / l[h];
    #pragma unroll
    for (int j = 0; j < 3; ++j){
      short4v pk;
      #pragma unroll
      for (int c = 0; c < 4; ++c) pk[c] = f2bf(acc[h][j][c] * inv);
      *(short4v*)(p_y + ((size_t)h * BSN + n) * EE + 4 * lane + 256 * j) = pk;
    }
  }
}

// ---------------------------------------------------------------------------
// m97-style 128x128 bf16 MFMA GEMM, BK=64, global_load_lds(16B) staging.
// A: [M][Kdim] bf16 row-major, Bt: [N][Kdim] bf16 (B transposed).
// MODE 0 (per-head, z=head): cat[m][768z+f] = bf16(gelu(x[m][f]+acc+addv[768z+f]))
// MODE 1 (split-K, z=half):  part[z][m][f] = acc (f32), epilogue separate.
// grid (M/128, N/128, Z), 256 threads (4 waves, each 64x64 = 4x4 frags).
// ---------------------------------------------------------------------------
template<int MODE>
__global__ __launch_bounds__(256) void k_gemm128(const short* __restrict__ A,
                                                 const short* __restrict__ Bt,
                                                 const float* __restrict__ addv,
                                                 const float* __restrict__ x,
                                                 void* __restrict__ out,
                                                 int Kdim, size_t strideA, size_t strideB){
  __shared__ short As[128 * 64];
  __shared__ short Bs[128 * 64];
  const int z = blockIdx.z;
  const short* Ah; const short* Bh; int kbeg, kend;
  if (MODE == 0){ Ah = A + strideA * z; Bh = Bt + strideB * z; kbeg = 0; kend = Kdim; }
  else          { Ah = A; Bh = Bt; kbeg = z * (Kdim >> 1); kend = kbeg + (Kdim >> 1); }

  const int tid = threadIdx.x;
  const int w = tid >> 6, lane = tid & 63;
  const int quad = lane >> 4, l16 = lane & 15;
  const int m0 = blockIdx.x * 128, n0 = blockIdx.y * 128;
  const int lr = lane >> 3;           // row within 8-row slab
  const int lc = (lane & 7) * 8;      // k-element offset (16B chunk)

  // staging pointers: wave w owns rows [w*32, w*32+32) of each tile
  const short* gA = Ah + (size_t)(m0 + w * 32 + lr) * Kdim + lc;
  const short* gB = Bh + (size_t)(n0 + w * 32 + lr) * Kdim + lc;
  short* lA = As + (w * 32) * 64;
  short* lB = Bs + (w * 32) * 64;

  float4v acc[4][4];
  #pragma unroll
  for (int mt = 0; mt < 4; ++mt)
    #pragma unroll
    for (int nt = 0; nt < 4; ++nt) acc[mt][nt] = (float4v){0.f, 0.f, 0.f, 0.f};

  const int wm = (w & 1) * 64, wn = (w >> 1) * 64;

  for (int k0 = kbeg; k0 < kend; k0 += 64){
    __syncthreads();
    #pragma unroll
    for (int i = 0; i < 4; ++i){
      gload_lds16(gA + (size_t)(8 * i) * Kdim + k0, lA + i * 8 * 64);
      gload_lds16(gB + (size_t)(8 * i) * Kdim + k0, lB + i * 8 * 64);
    }
    __syncthreads();
    #pragma unroll
    for (int kk = 0; kk < 64; kk += 32){
      short8 afr[4], bfr[4];
      #pragma unroll
      for (int nt = 0; nt < 4; ++nt)
        bfr[nt] = *(const short8*)(Bs + (wn + nt * 16 + l16) * 64 + kk + quad * 8);
      #pragma unroll
      for (int mt = 0; mt < 4; ++mt)
        afr[mt] = *(const short8*)(As + (wm + mt * 16 + l16) * 64 + kk + quad * 8);
      #pragma unroll
      for (int mt = 0; mt < 4; ++mt)
        #pragma unroll
        for (int nt = 0; nt < 4; ++nt)
          acc[mt][nt] = __builtin_amdgcn_mfma_f32_16x16x32_bf16(afr[mt], bfr[nt], acc[mt][nt], 0, 0, 0);
    }
  }

  if (MODE == 0){
    const float* addh = addv + 768 * z;
    #pragma unroll
    for (int nt = 0; nt < 4; ++nt){
      const int f = n0 + wn + nt * 16 + l16;
      const float add = addh[f];
      #pragma unroll
      for (int mt = 0; mt < 4; ++mt)
        #pragma unroll
        for (int rr = 0; rr < 4; ++rr){
          const int m = m0 + wm + mt * 16 + quad * 4 + rr;
          const float val = acc[mt][nt][rr] + add;
          const float xf = x[(size_t)m * EE + f];
          ((short*)out)[(size_t)m * (HH * EE) + 768 * z + f] = f2bf(gelu_tanh(xf + val));
        }
    }
  } else {
    float* po = (float*)out + (size_t)z * BSN * EE;
    #pragma unroll
    for (int nt = 0; nt < 4; ++nt){
      const int f = n0 + wn + nt * 16 + l16;
      #pragma unroll
      for (int mt = 0; mt < 4; ++mt)
        #pragma unroll
        for (int rr = 0; rr < 4; ++rr){
          const int m = m0 + wm + mt * 16 + quad * 4 + rr;
          po[(size_t)m * EE + f] = acc[mt][nt][rr];
        }
    }
  }
}

// ---------------------------------------------------------------------------
// epilogue for split-K GEMM1: out = x + gelu(p0 + p1 + bm)
// ---------------------------------------------------------------------------
__global__ __launch_bounds__(256) void k_ep(const float* __restrict__ part,
                                            const float* __restrict__ bm,
                                            const float* __restrict__ x,
                                            float* __restrict__ out){
  const size_t i = ((size_t)blockIdx.x * 256 + threadIdx.x) * 4;
  float4v p0 = *(const float4v*)(part + i);
  float4v p1 = *(const float4v*)(part + (size_t)BSN * EE + i);
  float4v xv = *(const float4v*)(x + i);
  float4v bv = *(const float4v*)(bm + (int)(i % EE));
  float4v o;
  #pragma unroll
  for (int c = 0; c < 4; ++c) o[c] = xv[c] + gelu_tanh(p0[c] + p1[c] + bv[c]);
  *(float4v*)(out + i) = o;
}

// ---------------------------------------------------------------------------
extern "C" void kernel_launch(void* const* d_in, const int* in_sizes, int n_in,
                              void* d_out, int out_size, void* d_ws, size_t ws_size,
                              hipStream_t stream){
  const float* x    = (const float*)d_in[0];
  const float* y    = (const float*)d_in[1];
  const float* g    = (const float*)d_in[2];
  const float* beta = (const float*)d_in[3];
  const float* W1   = (const float*)d_in[4];
  const float* b1   = (const float*)d_in[5];
  const float* W2y  = (const float*)d_in[7];   // W2x, b2 cancel in softmax
  const float* Wm   = (const float*)d_in[9];
  const float* bm   = (const float*)d_in[10];

  char* ws = (char*)d_ws;
  float* v    = (float*)(ws + 0);              // 4*768 f32
  float* b1p  = (float*)(ws + 12288);          // 4*768 f32
  short* W1t  = (short*)(ws + 24576);          // 4*768*768 bf16 (transposed)
  short* Wmt  = (short*)(ws + 4743168);        // 768*3072 bf16 (transposed)
  short* p_y  = (short*)(ws + 9461760);        // 4*2048*768 bf16
  short* catb = (short*)(ws + 22044672);       // 2048*3072 bf16
  float* part = (float*)(ws + 34627584);       // 2*2048*768 f32 split-K partials
  float* out  = (float*)d_out;

  k_v<<<dim3(768), dim3(256), 0, stream>>>(W1, W2y, g, b1, v, b1p);
  k_b1p_acc<<<dim3(256), dim3(256), 0, stream>>>(W1, beta, b1p);
  k_tW1<<<dim3(24, 24, 4), dim3(256), 0, stream>>>(W1, g, W1t);
  k_tWm<<<dim3(96, 24), dim3(256), 0, stream>>>(Wm, Wmt);
  k_pass_y<<<dim3(512), dim3(256), 0, stream>>>(y, v, p_y);
  k_gemm128<0><<<dim3(16, 6, 4), dim3(256), 0, stream>>>(
      p_y, W1t, b1p, x, (void*)catb, 768, (size_t)2048 * 768, (size_t)768 * 768);
  k_gemm128<1><<<dim3(16, 6, 2), dim3(256), 0, stream>>>(
      catb, Wmt, nullptr, nullptr, (void*)part, 3072, (size_t)0, (size_t)0);
  k_ep<<<dim3(1536), dim3(256), 0, stream>>>(part, bm, x, out);
}

// Round 5
// 428.334 us; speedup vs baseline: 1.0620x; 1.0620x over previous
//
#include <hip/hip_runtime.h>
#include <hip/hip_bf16.h>
#include <math.h>

#define EE 768
#define HH 4
#define KK 36
#define BSN 2048

typedef __attribute__((ext_vector_type(8))) short short8;
typedef __attribute__((ext_vector_type(4))) short short4v;
typedef __attribute__((ext_vector_type(4))) float float4v;

__device__ inline short f2bf(float x){
  return __builtin_bit_cast(short, __float2bfloat16(x));
}
__device__ inline float bf2f(short s){
  return __bfloat162float(__builtin_bit_cast(__hip_bfloat16, s));
}
__device__ inline float gelu_tanh(float x){
  // jax.nn.gelu default (approximate=True)
  float t = tanhf(0.79788456080286536f * (x + 0.044715f * x * x * x));
  return 0.5f * x * (1.0f + t);
}

// ---------------------------------------------------------------------------
// v[h][e] = g[h][e] * sum_f W1[h][e][f] * W2y[h][f]    (one wave per (h,e))
// also initializes b1p = b1 (first 12 blocks' worth of threads)
// ---------------------------------------------------------------------------
__global__ __launch_bounds__(256) void k_v(const float* __restrict__ W1,
                                           const float* __restrict__ W2y,
                                           const float* __restrict__ g,
                                           const float* __restrict__ b1,
                                           float* __restrict__ v,
                                           float* __restrict__ b1p){
  const int wid  = blockIdx.x * 4 + (threadIdx.x >> 6);
  const int lane = threadIdx.x & 63;
  const int h = wid / EE, e = wid % EE;
  const float* W  = W1 + ((size_t)h * EE + e) * EE;
  const float* wy = W2y + h * EE;
  float acc = 0.f;
  #pragma unroll
  for (int j = 0; j < 12; ++j){
    int f = lane + 64 * j;
    acc += W[f] * wy[f];
  }
  #pragma unroll
  for (int off = 32; off; off >>= 1) acc += __shfl_xor(acc, off);
  if (lane == 0) v[h * EE + e] = g[h * EE + e] * acc;

  int idx = blockIdx.x * 256 + threadIdx.x;
  if (idx < HH * EE) b1p[idx] = b1[idx];
}

// ---------------------------------------------------------------------------
// b1p[h][f] += sum_e beta[h][e] * W1[h][e][f]   (partial e-chunks + atomics)
// grid: 256 blocks = 4 h * 64 e-chunks of 12
// ---------------------------------------------------------------------------
__global__ __launch_bounds__(256) void k_b1p_acc(const float* __restrict__ W1,
                                                 const float* __restrict__ beta,
                                                 float* __restrict__ b1p){
  const int h   = blockIdx.x >> 6;
  const int ec0 = (blockIdx.x & 63) * 12;
  const float* W  = W1 + (size_t)h * EE * EE;
  const float* bt = beta + h * EE;
  const int f = threadIdx.x;
  float a0 = 0.f, a1 = 0.f, a2 = 0.f;
  #pragma unroll
  for (int e = ec0; e < ec0 + 12; ++e){
    float be = bt[e];
    const float* row = W + (size_t)e * EE;
    a0 += be * row[f];
    a1 += be * row[f + 256];
    a2 += be * row[f + 512];
  }
  atomicAdd(&b1p[h * EE + f],       a0);
  atomicAdd(&b1p[h * EE + f + 256], a1);
  atomicAdd(&b1p[h * EE + f + 512], a2);
}

// ---------------------------------------------------------------------------
// W1t[h][f][e] = bf16( g[h][e] * W1[h][e][f] )   (transposed, bf16)
// grid (24 e-tiles, 24 f-tiles, 4 h), 256 threads
// ---------------------------------------------------------------------------
__global__ __launch_bounds__(256) void k_tW1(const float* __restrict__ W1,
                                             const float* __restrict__ g,
                                             short* __restrict__ W1t){
  __shared__ float tile[32][33];
  const int h  = blockIdx.z;
  const int e0 = blockIdx.x * 32, f0 = blockIdx.y * 32;
  const int tx = threadIdx.x & 31, ty = threadIdx.x >> 5;
  const float* W = W1 + (size_t)h * EE * EE;
  #pragma unroll
  for (int i = 0; i < 4; ++i){
    int e = e0 + ty + 8 * i;
    tile[ty + 8 * i][tx] = W[(size_t)e * EE + f0 + tx] * g[h * EE + e];
  }
  __syncthreads();
  #pragma unroll
  for (int i = 0; i < 4; ++i){
    int f = f0 + ty + 8 * i;
    W1t[((size_t)h * EE + f) * EE + e0 + tx] = f2bf(tile[tx][ty + 8 * i]);
  }
}

// ---------------------------------------------------------------------------
// Wmt[f][c] = bf16( Wm[c][f] )   c in [0,3072), f in [0,768)
// grid (96 c-tiles, 24 f-tiles)
// ---------------------------------------------------------------------------
__global__ __launch_bounds__(256) void k_tWm(const float* __restrict__ Wm,
                                             short* __restrict__ Wmt){
  __shared__ float tile[32][33];
  const int c0 = blockIdx.x * 32, f0 = blockIdx.y * 32;
  const int tx = threadIdx.x & 31, ty = threadIdx.x >> 5;
  #pragma unroll
  for (int i = 0; i < 4; ++i){
    tile[ty + 8 * i][tx] = Wm[(size_t)(c0 + ty + 8 * i) * EE + f0 + tx];
  }
  __syncthreads();
  #pragma unroll
  for (int i = 0; i < 4; ++i){
    Wmt[(size_t)(f0 + ty + 8 * i) * (HH * EE) + c0 + tx] = f2bf(tile[tx][ty + 8 * i]);
  }
}

// ---------------------------------------------------------------------------
// Flash-style fused y pass: ONE WAVE PER ROW n. For each k-row: LN0 ->
// logits d_h = yn . v_h (x_/W2x/b2 cancel in softmax) -> online softmax
// -> acc_h += w * yn. No LDS, no barriers; 2-row register prefetch.
// ---------------------------------------------------------------------------
__global__ __launch_bounds__(256) void k_pass_y(const float* __restrict__ y,
                                                const float* __restrict__ v,
                                                short* __restrict__ p_y){
  const int wave = threadIdx.x >> 6, lane = threadIdx.x & 63;
  const int n = blockIdx.x * 4 + wave;
  const float* base = y + (size_t)n * KK * EE + 4 * lane;

  float4v vreg[HH][3];
  #pragma unroll
  for (int h = 0; h < HH; ++h)
    #pragma unroll
    for (int j = 0; j < 3; ++j)
      vreg[h][j] = *(const float4v*)(v + h * EE + 4 * lane + 256 * j);

  float4v acc[HH][3];
  #pragma unroll
  for (int h = 0; h < HH; ++h)
    #pragma unroll
    for (int j = 0; j < 3; ++j)
      acc[h][j] = (float4v){0.f, 0.f, 0.f, 0.f};
  float m[HH], l[HH];
  #pragma unroll
  for (int h = 0; h < HH; ++h){ m[h] = -INFINITY; l[h] = 0.f; }

  float4v bufA[3], bufB[3];
  #pragma unroll
  for (int j = 0; j < 3; ++j) bufA[j] = *(const float4v*)(base + 256 * j);
  #pragma unroll
  for (int j = 0; j < 3; ++j) bufB[j] = *(const float4v*)(base + EE + 256 * j);

  #pragma unroll 2
  for (int k = 0; k < KK; ++k){
    float4v cur[3];
    #pragma unroll
    for (int j = 0; j < 3; ++j) cur[j] = bufA[j];
    #pragma unroll
    for (int j = 0; j < 3; ++j) bufA[j] = bufB[j];
    if (k + 2 < KK){
      const float* rp = base + (size_t)(k + 2) * EE;
      #pragma unroll
      for (int j = 0; j < 3; ++j) bufB[j] = *(const float4v*)(rp + 256 * j);
    }

    float s = 0.f, s2 = 0.f;
    #pragma unroll
    for (int j = 0; j < 3; ++j)
      #pragma unroll
      for (int c = 0; c < 4; ++c){ float t = cur[j][c]; s += t; s2 += t * t; }
    #pragma unroll
    for (int off = 32; off; off >>= 1){
      s  += __shfl_xor(s, off);
      s2 += __shfl_xor(s2, off);
    }
    const float mu = s * (1.f / EE);
    const float rs = rsqrtf(s2 * (1.f / EE) - mu * mu + 1e-5f);

    float d[HH] = {0.f, 0.f, 0.f, 0.f};
    #pragma unroll
    for (int j = 0; j < 3; ++j)
      #pragma unroll
      for (int c = 0; c < 4; ++c){
        float t = (cur[j][c] - mu) * rs;
        cur[j][c] = t;
        d[0] += t * vreg[0][j][c];
        d[1] += t * vreg[1][j][c];
        d[2] += t * vreg[2][j][c];
        d[3] += t * vreg[3][j][c];
      }
    #pragma unroll
    for (int off = 32; off; off >>= 1){
      d[0] += __shfl_xor(d[0], off);
      d[1] += __shfl_xor(d[1], off);
      d[2] += __shfl_xor(d[2], off);
      d[3] += __shfl_xor(d[3], off);
    }

    #pragma unroll
    for (int h = 0; h < HH; ++h){
      if (d[h] > m[h]){
        float sc = __expf(m[h] - d[h]);   // first iter: exp(-inf)=0
        l[h] *= sc;
        #pragma unroll
        for (int j = 0; j < 3; ++j)
          #pragma unroll
          for (int c = 0; c < 4; ++c) acc[h][j][c] *= sc;
        m[h] = d[h];
      }
      float w = __expf(d[h] - m[h]);
      l[h] += w;
      #pragma unroll
      for (int j = 0; j < 3; ++j)
        #pragma unroll
        for (int c = 0; c < 4; ++c) acc[h][j][c] += w * cur[j][c];
    }
  }

  #pragma unroll
  for (int h = 0; h < HH; ++h){
    const float inv = 1.f / l[h];
    #pragma unroll
    for (int j = 0; j < 3; ++j){
      short4v pk;
      #pragma unroll
      for (int c = 0; c < 4; ++c) pk[c] = f2bf(acc[h][j][c] * inv);
      *(short4v*)(p_y + ((size_t)h * BSN + n) * EE + 4 * lane + 256 * j) = pk;
    }
  }
}

// ---------------------------------------------------------------------------
// 64x64-tile bf16 MFMA GEMM, C = A @ Bt^T with fused epilogue.
// A: [M][Kdim] bf16 row-major. Bt: [N][Kdim] bf16 (i.e. B transposed).
// MODE 0 (z=head): cat[m][768z+f] = bf16( gelu(x[m][f] + acc + addv[768z+f]) )
// MODE 1 (z=K-half, split-K): part[z][m][f] = acc (f32); epilogue separate.
// grid (M/64, N/64, Z)
// ---------------------------------------------------------------------------
template<int MODE>
__global__ __launch_bounds__(256) void k_gemm(const short* __restrict__ A,
                                              const short* __restrict__ Bt,
                                              const float* __restrict__ addv,
                                              const float* __restrict__ x,
                                              void* __restrict__ out,
                                              int Kdim, size_t strideA, size_t strideB){
  __shared__ short As[64][72];
  __shared__ short Bs[64][72];
  const int z = blockIdx.z;
  const short* Ah; const short* Bh; int kbeg, kend;
  if (MODE == 0){ Ah = A + strideA * z; Bh = Bt + strideB * z; kbeg = 0; kend = Kdim; }
  else          { Ah = A; Bh = Bt; kbeg = z * (Kdim >> 1); kend = kbeg + (Kdim >> 1); }

  const int tid = threadIdx.x;
  const int wave = tid >> 6, lane = tid & 63;
  const int quad = lane >> 4, l16 = lane & 15;
  const int m0 = blockIdx.x * 64, n0 = blockIdx.y * 64;
  const int r = tid >> 3, c8 = (tid & 7) * 8;

  float4v acc[4];
  #pragma unroll
  for (int t = 0; t < 4; ++t) acc[t] = (float4v){0.f, 0.f, 0.f, 0.f};

  const short* Ap0 = Ah + (size_t)(m0 + r) * Kdim + c8;
  const short* Ap1 = Ah + (size_t)(m0 + r + 32) * Kdim + c8;
  const short* Bp0 = Bh + (size_t)(n0 + r) * Kdim + c8;
  const short* Bp1 = Bh + (size_t)(n0 + r + 32) * Kdim + c8;

  for (int k0 = kbeg; k0 < kend; k0 += 64){
    short8 a0 = *(const short8*)(Ap0 + k0);
    short8 a1 = *(const short8*)(Ap1 + k0);
    short8 b0 = *(const short8*)(Bp0 + k0);
    short8 b1 = *(const short8*)(Bp1 + k0);
    __syncthreads();
    *(short8*)(&As[r][c8])      = a0;
    *(short8*)(&As[r + 32][c8]) = a1;
    *(short8*)(&Bs[r][c8])      = b0;
    *(short8*)(&Bs[r + 32][c8]) = b1;
    __syncthreads();
    #pragma unroll
    for (int kk = 0; kk < 64; kk += 32){
      short8 bf = *(const short8*)(&Bs[16 * wave + l16][kk + quad * 8]);
      #pragma unroll
      for (int t = 0; t < 4; ++t){
        short8 af = *(const short8*)(&As[16 * t + l16][kk + quad * 8]);
        acc[t] = __builtin_amdgcn_mfma_f32_16x16x32_bf16(af, bf, acc[t], 0, 0, 0);
      }
    }
  }

  const int f = n0 + 16 * wave + l16;
  if (MODE == 0){
    const float add = addv[768 * z + f];
    #pragma unroll
    for (int t = 0; t < 4; ++t){
      #pragma unroll
      for (int rr = 0; rr < 4; ++rr){
        const int m = m0 + 16 * t + quad * 4 + rr;
        const float val = acc[t][rr] + add;
        const float xf = x[(size_t)m * EE + f];
        ((short*)out)[(size_t)m * (HH * EE) + 768 * z + f] = f2bf(gelu_tanh(xf + val));
      }
    }
  } else {
    float* po = (float*)out + (size_t)z * BSN * EE;
    #pragma unroll
    for (int t = 0; t < 4; ++t){
      #pragma unroll
      for (int rr = 0; rr < 4; ++rr){
        const int m = m0 + 16 * t + quad * 4 + rr;
        po[(size_t)m * EE + f] = acc[t][rr];
      }
    }
  }
}

// ---------------------------------------------------------------------------
// epilogue for split-K GEMM1: out = x + gelu(p0 + p1 + bm)
// ---------------------------------------------------------------------------
__global__ __launch_bounds__(256) void k_ep(const float* __restrict__ part,
                                            const float* __restrict__ bm,
                                            const float* __restrict__ x,
                                            float* __restrict__ out){
  const size_t i = ((size_t)blockIdx.x * 256 + threadIdx.x) * 4;
  float4v p0 = *(const float4v*)(part + i);
  float4v p1 = *(const float4v*)(part + (size_t)BSN * EE + i);
  float4v xv = *(const float4v*)(x + i);
  float4v bv = *(const float4v*)(bm + (int)(i % EE));
  float4v o;
  #pragma unroll
  for (int c = 0; c < 4; ++c) o[c] = xv[c] + gelu_tanh(p0[c] + p1[c] + bv[c]);
  *(float4v*)(out + i) = o;
}

// ---------------------------------------------------------------------------
extern "C" void kernel_launch(void* const* d_in, const int* in_sizes, int n_in,
                              void* d_out, int out_size, void* d_ws, size_t ws_size,
                              hipStream_t stream){
  const float* x    = (const float*)d_in[0];
  const float* y    = (const float*)d_in[1];
  const float* g    = (const float*)d_in[2];
  const float* beta = (const float*)d_in[3];
  const float* W1   = (const float*)d_in[4];
  const float* b1   = (const float*)d_in[5];
  const float* W2y  = (const float*)d_in[7];   // W2x, b2 cancel in softmax
  const float* Wm   = (const float*)d_in[9];
  const float* bm   = (const float*)d_in[10];

  char* ws = (char*)d_ws;
  float* v    = (float*)(ws + 0);              // 4*768 f32
  float* b1p  = (float*)(ws + 12288);          // 4*768 f32
  short* W1t  = (short*)(ws + 24576);          // 4*768*768 bf16 (transposed)
  short* Wmt  = (short*)(ws + 4743168);        // 768*3072 bf16 (transposed)
  short* p_y  = (short*)(ws + 9461760);        // 4*2048*768 bf16
  short* catb = (short*)(ws + 22044672);       // 2048*3072 bf16
  float* part = (float*)(ws + 34627584);       // 2*2048*768 f32 split-K partials
  float* out  = (float*)d_out;

  k_v<<<dim3(768), dim3(256), 0, stream>>>(W1, W2y, g, b1, v, b1p);
  k_b1p_acc<<<dim3(256), dim3(256), 0, stream>>>(W1, beta, b1p);
  k_tW1<<<dim3(24, 24, 4), dim3(256), 0, stream>>>(W1, g, W1t);
  k_tWm<<<dim3(96, 24), dim3(256), 0, stream>>>(Wm, Wmt);
  k_pass_y<<<dim3(512), dim3(256), 0, stream>>>(y, v, p_y);
  k_gemm<0><<<dim3(32, 12, 4), dim3(256), 0, stream>>>(
      p_y, W1t, b1p, x, (void*)catb, 768, (size_t)2048 * 768, (size_t)768 * 768);
  k_gemm<1><<<dim3(32, 12, 2), dim3(256), 0, stream>>>(
      catb, Wmt, nullptr, nullptr, (void*)part, 3072, (size_t)0, (size_t)0);
  k_ep<<<dim3(1536), dim3(256), 0, stream>>>(part, bm, x, out);
}